// Round 1
// 1918.802 us; speedup vs baseline: 1.1550x; 1.1550x over previous
//
#include <hip/hip_runtime.h>
#include <stdint.h>

#define TT 128
#define BB 128
#define NN 1024

// World model (verified bit-exact in R9):
//   tx: packed bf16 storage (runtime-probed each launch; probe also handles f32),
//   W : f32 storage, bf16-rounded values; b: f32; out: f32.
//   Reference recurrent sum: OpenBLAS sgemm kc=384 panels, sequential-k
//   single accumulator per panel, a = (P0 + P1) + P2.  With binary y all
//   products are exact, so this association is reproduced exactly.
//
// R10 changes (latency attack; association untouched):
//   - per-panel lists at fixed offsets {0,384,768}, padded to x32 with
//     sentinel k=1024 -> zeroed row appended after WtBf (acc+0.0f is exact)
//   - 32 outstanding gather loads per batch (was 8), list read via
//     ds_read_b128 (8 entries/read, was 8x ds_read_u16)
//   - SYNC3 removed (SYNC1 of step t+1 already orders gather(t) reads
//     before lst(t+1) writes)
//   - nontemporal tx loads / out stores to keep 2MB W^T L2-resident

typedef unsigned short ushort8 __attribute__((ext_vector_type(8)));

__device__ __forceinline__ float bfbits2f(uint32_t lo16) {
  union { uint32_t i; float f; } c;
  c.i = lo16 << 16;
  return c.f;
}

// ---------------------------------------------------------------------------
// Kernel 0: in-place f32 transpose of W (tile-pair swap)  +  bf16 repack of
// W^T into ws  +  losslessness check (dirty flag set if any f32 word has
// nonzero low 16 bits — then the gather kernel uses the f32 path).
// ---------------------------------------------------------------------------
__global__ __launch_bounds__(256) void w_transpose_repack(
    float* __restrict__ W, uint16_t* __restrict__ WtBf,
    uint32_t* __restrict__ dirty) {
  __shared__ float ta[32][33];
  __shared__ float tb[32][33];

  int rem = blockIdx.x;
  int I = 0;
  while (rem >= (32 - I)) { rem -= (32 - I); ++I; }
  const int J = I + rem;

  const int lx = threadIdx.x & 31;
  const int ly = threadIdx.x >> 5;  // 0..7
  uint32_t bad = 0;

  if (I == J) {
#pragma unroll
    for (int i = 0; i < 4; ++i)
      ta[ly + i * 8][lx] = W[(I * 32 + ly + i * 8) * NN + J * 32 + lx];
    __syncthreads();
#pragma unroll
    for (int i = 0; i < 4; ++i) {
      const int idx = (I * 32 + ly + i * 8) * NN + J * 32 + lx;
      const float v = ta[lx][ly + i * 8];
      const uint32_t bits = __float_as_uint(v);
      W[idx] = v;
      WtBf[idx] = (uint16_t)(bits >> 16);
      bad |= (bits & 0xFFFFu);
    }
  } else {
#pragma unroll
    for (int i = 0; i < 4; ++i) {
      ta[ly + i * 8][lx] = W[(I * 32 + ly + i * 8) * NN + J * 32 + lx];
      tb[ly + i * 8][lx] = W[(J * 32 + ly + i * 8) * NN + I * 32 + lx];
    }
    __syncthreads();
#pragma unroll
    for (int i = 0; i < 4; ++i) {
      const int idxA = (J * 32 + ly + i * 8) * NN + I * 32 + lx;
      const float va = ta[lx][ly + i * 8];
      const uint32_t bitsA = __float_as_uint(va);
      W[idxA] = va;
      WtBf[idxA] = (uint16_t)(bitsA >> 16);
      bad |= (bitsA & 0xFFFFu);

      const int idxB = (I * 32 + ly + i * 8) * NN + J * 32 + lx;
      const float vb = tb[lx][ly + i * 8];
      const uint32_t bitsB = __float_as_uint(vb);
      W[idxB] = vb;
      WtBf[idxB] = (uint16_t)(bitsB >> 16);
      bad |= (bitsB & 0xFFFFu);
    }
  }
  const unsigned long long bm = __ballot(bad != 0);
  if ((threadIdx.x & 63) == 0 && bm) atomicOr(dirty, 1u);
}

// ---------------------------------------------------------------------------
// Kernel 1: per-sample LIF, 1024 threads (1 neuron/thread, 16 waves/CU).
// Per step: ballot-compacted per-panel active lists (ascending k within each
// panel by construction), sentinel-padded to x32, then 32-wide gather batches
// with sequential f32 adds in k order (bit-identical to R9's association).
// ---------------------------------------------------------------------------
__global__ __launch_bounds__(1024) void lif_persample(
    const void* __restrict__ tx_raw, const float* __restrict__ bias,
    const float* __restrict__ WtF32, const uint16_t* __restrict__ WtBf,
    const uint32_t* __restrict__ dirty, float* __restrict__ out) {
  const int b = blockIdx.x;
  const int tid = threadIdx.x;     // == neuron index n == recurrent index k
  const int lane = tid & 63;
  const int wv = tid >> 6;         // 0..15

  __shared__ uint16_t lst[NN] __attribute__((aligned(16)));
  __shared__ int wcnt[16];
  __shared__ int sprobe;

  // ---- runtime tx-storage probe (bf16-packed vs f32), as verified in R9 ----
  if (tid == 0) sprobe = 0;
  __syncthreads();
  {
    const uint32_t* txw = (const uint32_t*)tx_raw;
    int local = 0;
#pragma unroll
    for (int i = 0; i < 2; ++i) {
      const uint32_t f = (txw[tid * 2 + i] >> 7) & 0xFFu;
      local += (f >= 0x74u && f < 0x81u) ? 1 : 0;
    }
    atomicAdd(&sprobe, local);
  }
  __syncthreads();
  const bool tx_is_bf16 = (sprobe > 1024);   // of 2048 sampled words
  const bool w_bf = (*dirty == 0u);          // bf16 repack lossless?

  const uint16_t* __restrict__ txh = (const uint16_t*)tx_raw;
  const float* __restrict__ txf = (const float*)tx_raw;
  const float bz = bias[tid];

  // panel of this thread's wave: waves 0..5 -> P0 (k<384), 6..11 -> P1, 12..15 -> P2
  const int pidx = (wv < 6) ? 0 : ((wv < 12) ? 1 : 2);
  const int pw0 = (pidx == 0) ? 0 : ((pidx == 1) ? 6 : 12);

  // per-thread row bases (encourage saddr-form loads: scalar k-base + shared voffset)
  const uint16_t* __restrict__ rowB = WtBf + tid;
  const float* __restrict__ rowF = WtF32 + tid;

  float v = 0.0f;   // membrane (REST = 0)
  int y = 0;        // previous spike

  // 32-wide gather over a sentinel-padded panel list [pbase, pbase+cnt),
  // cnt % 32 == 0. Ascending k, ONE accumulator, adds strictly in list
  // order (exact reference association; sentinel rows add +0.0f exactly).
  auto gB = [&](int pbase, int cnt) -> float {
    float acc = 0.0f;
    for (int i = 0; i < cnt; i += 32) {
      const ushort8* lp = (const ushort8*)(lst + pbase + i);
      const ushort8 a0 = lp[0];
      const ushort8 a1 = lp[1];
      const ushort8 a2 = lp[2];
      const ushort8 a3 = lp[3];
      float wbuf[32];
#pragma unroll
      for (int u = 0; u < 8; ++u) {
        const int k = __builtin_amdgcn_readfirstlane((int)a0[u]);
        wbuf[u] = bfbits2f((uint32_t)rowB[k << 10]);
      }
#pragma unroll
      for (int u = 0; u < 8; ++u) {
        const int k = __builtin_amdgcn_readfirstlane((int)a1[u]);
        wbuf[8 + u] = bfbits2f((uint32_t)rowB[k << 10]);
      }
#pragma unroll
      for (int u = 0; u < 8; ++u) {
        const int k = __builtin_amdgcn_readfirstlane((int)a2[u]);
        wbuf[16 + u] = bfbits2f((uint32_t)rowB[k << 10]);
      }
#pragma unroll
      for (int u = 0; u < 8; ++u) {
        const int k = __builtin_amdgcn_readfirstlane((int)a3[u]);
        wbuf[24 + u] = bfbits2f((uint32_t)rowB[k << 10]);
      }
#pragma unroll
      for (int u = 0; u < 32; ++u) acc += wbuf[u];
    }
    return acc;
  };

  // f32 fallback (cold path): unpadded bounds [s, e), old 8-wide structure.
  auto gF = [&](int s, int e) -> float {
    float acc = 0.0f;
    int i = s;
    for (; i + 8 <= e; i += 8) {
      float w[8];
#pragma unroll
      for (int u = 0; u < 8; ++u) {
        const int k = __builtin_amdgcn_readfirstlane((int)lst[i + u]);
        w[u] = rowF[k << 10];
      }
#pragma unroll
      for (int u = 0; u < 8; ++u) acc += w[u];
    }
    for (; i < e; ++i) {
      const int k = __builtin_amdgcn_readfirstlane((int)lst[i]);
      acc += rowF[k << 10];
    }
    return acc;
  };

  for (int t = 0; t < TT; ++t) {
    // ---- build compacted per-panel active lists (ascending k) ----
    const unsigned long long m = __ballot(y);
    if (lane == 0) wcnt[wv] = __popcll(m);
    __syncthreads();  // SYNC1: wcnt visible (also orders lst(t) reads vs lst(t+1) writes)
    int base = 0, c0 = 0, c1 = 0, c2 = 0;
#pragma unroll
    for (int w = 0; w < 16; ++w) {
      const int c = wcnt[w];
      c0 += (w < 6) ? c : 0;
      c1 += (w >= 6 && w < 12) ? c : 0;
      c2 += (w >= 12) ? c : 0;
      base += (w >= pw0 && w < wv) ? c : 0;  // prefix within my panel
    }
    if (y) {
      const int below = __builtin_amdgcn_mbcnt_hi(
          (uint32_t)(m >> 32), __builtin_amdgcn_mbcnt_lo((uint32_t)m, 0));
      lst[pidx * 384 + base + below] = (uint16_t)tid;
    }
    // sentinel padding to x32 per panel (k=NN -> zeroed row, +0.0f exact)
    if (tid < 96) {
      const int p = tid >> 5, j = tid & 31;
      const int c = (p == 0) ? c0 : ((p == 1) ? c1 : c2);
      if (c + j < ((c + 31) & ~31)) lst[p * 384 + c + j] = (uint16_t)NN;
    }
    __syncthreads();  // SYNC2: lst complete

    // ---- recurrent term: (P0 + P1) + P2, sequential k within panels ----
    float P0, P1, P2;
    if (w_bf) {
      P0 = gB(0, (c0 + 31) & ~31);
      P1 = gB(384, (c1 + 31) & ~31);
      P2 = gB(768, (c2 + 31) & ~31);
    } else {
      P0 = gF(0, c0);
      P1 = gF(384, 384 + c1);
      P2 = gF(768, 768 + c2);
    }
    const float a = (P0 + P1) + P2;

    // ---- LIF update, reference op order, f32 ----
    const int off = (t * BB + b) * NN + tid;
    const float xx = tx_is_bf16
        ? bfbits2f((uint32_t)__builtin_nontemporal_load(&txh[off]))
        : __builtin_nontemporal_load(&txf[off]);
    const float xv = (xx + a) + bz;
    v = (y ? 0.0f : 0.5f * v) + xv;
    y = (v > 0.5f);

    __builtin_nontemporal_store(y ? 1.0f : 0.0f, &out[off]);
    // SYNC3 removed: a wave writes lst(t+1) only after SYNC1(t+1), which it
    // can only pass once ALL waves finished gather(t). wcnt(t+1) writes are
    // ordered against wcnt(t) reads by SYNC2(t).
  }
}

extern "C" void kernel_launch(void* const* d_in, const int* in_sizes, int n_in,
                              void* d_out, int out_size, void* d_ws, size_t ws_size,
                              hipStream_t stream) {
  // Inputs by element count: tx = 128*128*1024 (bf16-packed),
  // W = 1024*1024 (f32, bf16-valued), b = 1024 (f32).
  const void* tx = nullptr;
  float* W = nullptr;
  const float* bs = nullptr;
  for (int i = 0; i < n_in; ++i) {
    if (in_sizes[i] == TT * BB * NN) tx = d_in[i];
    else if (in_sizes[i] == NN * NN) W = (float*)d_in[i];
    else if (in_sizes[i] == NN) bs = (const float*)d_in[i];
  }
  float* out = (float*)d_out;                     // [T, B, N] f32 spikes

  // Workspace layout: [0,2MB) = bf16 W^T (1024 rows); [2MB,2MB+2KB) = zero
  // row (sentinel k=1024); dirty flag after that.
  uint16_t* WtBf = (uint16_t*)d_ws;
  uint16_t* zrow = WtBf + NN * NN;                // row index 1024
  uint32_t* dirty = (uint32_t*)((char*)d_ws + 2u * 1024u * 1024u + 2048u);

  // ws is poisoned 0xAA each launch — clear dirty flag and zero the sentinel row.
  hipMemsetAsync(dirty, 0, sizeof(uint32_t), stream);
  hipMemsetAsync(zrow, 0, NN * sizeof(uint16_t), stream);

  w_transpose_repack<<<dim3(528), dim3(256), 0, stream>>>(W, WtBf, dirty);
  lif_persample<<<dim3(BB), dim3(1024), 0, stream>>>(tx, bs, W, WtBf, dirty, out);
}